// Round 10
// baseline (1526.996 us; speedup 1.0000x reference)
//
#include <hip/hip_runtime.h>
#include <stdint.h>

#define HD 128
#define EE 300000
#define NROWS 1528000   // sum n_dst over 22 active relations (grouped by dst)
#define NEDGE 6600000   // 22 * EE
#define NB 128          // buckets per relation
#define ATILE 4096      // edges per bucketing workgroup
#define AWG 74          // ceil(EE / ATILE)

typedef __attribute__((ext_vector_type(8))) short bf16x8;
typedef __attribute__((ext_vector_type(4))) float f32x4;
typedef __attribute__((ext_vector_type(8))) unsigned short u16x8;

static __device__ __forceinline__ unsigned short f2bf(float x) {
  union { float f; unsigned u; } v; v.f = x;
  unsigned r = v.u + 0x7FFFu + ((v.u >> 16) & 1u);
  return (unsigned short)(r >> 16);
}
static __device__ __forceinline__ float bf2f(unsigned short h) {
  union { unsigned u; float f; } v; v.u = ((unsigned)h) << 16;
  return v.f;
}

// ---------------- weight pre-sum (WrSum per (layer,type), blSum) ----------------
struct WSumArgs {
  const float* Wr;   // [2][26][128][128]
  const float* bl;   // [2][26][128]
  float* WrSum;      // [2][10][128][128]
  float* blSum;      // [2][10][128]
  unsigned int mask[2][10];
};

__global__ __launch_bounds__(256) void wsum_kernel(WSumArgs a) {
  int lt  = blockIdx.x >> 6;
  int blk = blockIdx.x & 63;
  int layer = lt / 10, type = lt % 10;
  unsigned m = a.mask[layer][type];
  int idx = blk * 256 + threadIdx.x;   // 0..16383
  float s = 0.f;
  for (int r = 0; r < 26; ++r)
    if (m & (1u << r)) s += a.Wr[((size_t)(layer * 26 + r) << 14) + idx];
  a.WrSum[((size_t)(layer * 10 + type) << 14) + idx] = s;
  if (idx < HD) {
    float b = 0.f;
    for (int r = 0; r < 26; ++r)
      if (m & (1u << r)) b += a.bl[(size_t)(layer * 26 + r) * HD + idx];
    a.blSum[(size_t)(layer * 10 + type) * HD + idx] = b;
  }
}

// ---------------- weight transpose+bf16 prep: wt[m][n][k] = bf16(src[m][k][n]) ----------------
struct WtPrepArgs {
  const float* Wl;     // [52][128][128]
  const float* WrSum;  // [20][128][128]
  unsigned short* wt;  // [36][128][128] (n-major, k contiguous)
  int code[36];        // <100: Wl flat index; >=100: WrSum flat index - 100
};

__global__ __launch_bounds__(256) void wtprep_kernel(WtPrepArgs a) {
  int m = blockIdx.x >> 4;
  int chunk = blockIdx.x & 15;
  int idx = chunk * 256 + threadIdx.x;   // float4 index 0..4095
  int c = a.code[m];
  const float* src = (c < 100) ? a.Wl + ((size_t)c << 14)
                               : a.WrSum + ((size_t)(c - 100) << 14);
  int k = idx >> 5, n0 = (idx & 31) << 2;
  float4 v = *(const float4*)(src + (size_t)k * HD + n0);
  unsigned short* d = a.wt + ((size_t)m << 14);
  d[(size_t)(n0 + 0) * HD + k] = f2bf(v.x);
  d[(size_t)(n0 + 1) * HD + k] = f2bf(v.y);
  d[(size_t)(n0 + 2) * HD + k] = f2bf(v.z);
  d[(size_t)(n0 + 3) * HD + k] = f2bf(v.w);
}

// ---------------- bucketed CSR build ----------------
struct BktArgs {
  const int* ei[13];
  unsigned* bkt;     // [NEDGE] packed entries (dstlow<<18)|src
  int* bktCnt;       // [22*NB]
  int* bktCur;       // [22*NB]
  int rel[22];
  int shiftv[22];
};

__global__ __launch_bounds__(256) void bktcount_kernel(BktArgs a) {
  __shared__ int cnt[NB];
  int ri = blockIdx.x / AWG;
  int tile = (blockIdx.x % AWG) * ATILE;
  int t = threadIdx.x;
  if (t < NB) cnt[t] = 0;
  __syncthreads();
  int r = a.rel[ri];
  const int* ei = a.ei[r >> 1];
  int flip = r & 1, sh = a.shiftv[ri];
  #pragma unroll
  for (int j = 0; j < 16; ++j) {
    int e = tile + j * 256 + t;
    if (e < EE) {
      int dst = flip ? ei[e] : ei[EE + e];
      atomicAdd(&cnt[dst >> sh], 1);
    }
  }
  __syncthreads();
  if (t < NB && cnt[t]) atomicAdd(&a.bktCnt[ri * NB + t], cnt[t]);
}

__global__ __launch_bounds__(256) void bktfill_kernel(BktArgs a) {
  __shared__ int cnt[NB];
  __shared__ int base[NB];
  int ri = blockIdx.x / AWG;
  int tile = (blockIdx.x % AWG) * ATILE;
  int t = threadIdx.x;
  if (t < NB) cnt[t] = 0;
  __syncthreads();
  int r = a.rel[ri];
  const int* ei = a.ei[r >> 1];
  int flip = r & 1, sh = a.shiftv[ri];
  unsigned mask = (1u << sh) - 1u;
  unsigned pj[16]; int bj[16];
  #pragma unroll
  for (int j = 0; j < 16; ++j) {
    int e = tile + j * 256 + t;
    if (e < EE) {
      int src = flip ? ei[EE + e] : ei[e];
      int dst = flip ? ei[e] : ei[EE + e];
      int b = dst >> sh;
      pj[j] = (((unsigned)dst & mask) << 18) | (unsigned)src;
      bj[j] = b;
      atomicAdd(&cnt[b], 1);
    } else bj[j] = -1;
  }
  __syncthreads();
  if (t < NB) base[t] = cnt[t] ? atomicAdd(&a.bktCur[ri * NB + t], cnt[t]) : 0;
  __syncthreads();
  if (t < NB) cnt[t] = base[t];
  __syncthreads();
  #pragma unroll
  for (int j = 0; j < 16; ++j) {
    if (bj[j] >= 0) {
      int pos = atomicAdd(&cnt[bj[j]], 1);
      a.bkt[pos] = pj[j];
    }
  }
}

struct PlaceArgs {
  const unsigned* bkt;
  const int* bktRp;   // [22*NB+1]
  int* cntG;          // [NROWS]
  const int* rp;      // [NROWS+1]
  int* col;           // [NEDGE]
  int segOff[22];
  int shiftv[22];
  int nDst[22];
};

__global__ __launch_bounds__(256) void rowcount_kernel(PlaceArgs a) {
  __shared__ int cnt[2048];
  int bx = blockIdx.x;
  int ri = bx >> 7, b = bx & (NB - 1);
  int sh = a.shiftv[ri], nd = a.nDst[ri];
  int rowLo = b << sh;
  if (rowLo >= nd) return;
  int rows = min(1 << sh, nd - rowLo);
  int t = threadIdx.x;
  for (int k = t; k < rows; k += 256) cnt[k] = 0;
  __syncthreads();
  int s = a.bktRp[bx], e = a.bktRp[bx + 1];
  for (int i = s + t; i < e; i += 256) atomicAdd(&cnt[a.bkt[i] >> 18], 1);
  __syncthreads();
  int rowBase = a.segOff[ri] + rowLo;
  for (int k = t; k < rows; k += 256) a.cntG[rowBase + k] = cnt[k];
}

__global__ __launch_bounds__(256) void place_kernel(PlaceArgs a) {
  __shared__ int cur[2048];
  int bx = blockIdx.x;
  int ri = bx >> 7, b = bx & (NB - 1);
  int sh = a.shiftv[ri], nd = a.nDst[ri];
  int rowLo = b << sh;
  if (rowLo >= nd) return;
  int rows = min(1 << sh, nd - rowLo);
  int t = threadIdx.x;
  int rowBase = a.segOff[ri] + rowLo;
  for (int k = t; k < rows; k += 256) cur[k] = a.rp[rowBase + k];
  __syncthreads();
  int s = a.bktRp[bx], e = a.bktRp[bx + 1];
  for (int i = s + t; i < e; i += 256) {
    unsigned u = a.bkt[i];
    int pos = atomicAdd(&cur[u >> 18], 1);
    a.col[pos] = (int)(u & 0x3FFFFu);
  }
}

// ---------------- scans ----------------
__global__ __launch_bounds__(256) void scan_blk(const int* cnt, int* rp, int* bsum, int n) {
  __shared__ int sh[256];
  int t = threadIdx.x;
  int base = blockIdx.x * 2048 + t * 8;
  int v[8]; int s = 0;
  #pragma unroll
  for (int j = 0; j < 8; ++j) { int idx = base + j; v[j] = (idx < n) ? cnt[idx] : 0; s += v[j]; }
  sh[t] = s; __syncthreads();
  for (int d = 1; d < 256; d <<= 1) {
    int x = (t >= d) ? sh[t - d] : 0;
    __syncthreads();
    sh[t] += x;
    __syncthreads();
  }
  int excl = sh[t] - s;
  if (t == 255) bsum[blockIdx.x] = sh[255];
  int run = excl;
  #pragma unroll
  for (int j = 0; j < 8; ++j) { int idx = base + j; if (idx < n) rp[idx] = run; run += v[j]; }
}

__global__ __launch_bounds__(1024) void scan_top(int* bsum, int nb) {
  __shared__ int sh[1024];
  int t = threadIdx.x;
  int s = (t < nb) ? bsum[t] : 0;
  sh[t] = s; __syncthreads();
  for (int d = 1; d < 1024; d <<= 1) {
    int x = (t >= d) ? sh[t - d] : 0;
    __syncthreads();
    sh[t] += x;
    __syncthreads();
  }
  if (t < nb) bsum[t] = sh[t] - s;
}

__global__ __launch_bounds__(256) void scan_add(int* rp, int* cur, const int* bsum, int n, int total) {
  int i = blockIdx.x * 256 + threadIdx.x;
  if (i < n) { int v = rp[i] + bsum[i >> 11]; rp[i] = v; cur[i] = v; }
  if (i == 0) rp[n] = total;
}

// ---------------- bf16 MFMA GEMM (W-resident grid-stride) ----------------
// C[M x 128] = A[M x 128] @ W[128 x 128] (+bias). W staged to LDS ONCE per block;
// block loops over 64-row tiles with stride gridDim.
struct MGemmArgs { const void* A; const unsigned short* Wt; const float* bias; void* C;
                   int M; int outBf16; int inBf16; };

__global__ __launch_bounds__(256) void mgemm_kernel(MGemmArgs g) {
  __shared__ unsigned short As[64 * HD];   // [r][k] bf16, byte ^ ((r&7)<<4)
  __shared__ unsigned short Wsm[HD * HD];  // [n][k] bf16, byte ^ ((n&7)<<4)
  const int t = threadIdx.x;

  // stage W once (8 x 16B per thread)
  #pragma unroll
  for (int it = 0; it < 8; ++it) {
    int i8 = t + it * 256;
    int byteoff = i8 << 4;
    int n = byteoff >> 8;
    u16x8 w = *(const u16x8*)((const char*)g.Wt + byteoff);
    *(u16x8*)((char*)Wsm + (byteoff ^ ((n & 7) << 4))) = w;
  }

  const int wv = t >> 6;
  const int lane = t & 63;
  const int lr = lane & 15;
  const int lk = lane >> 4;
  const int tiles = (g.M + 63) >> 6;

  for (int tile = blockIdx.x; tile < tiles; tile += gridDim.x) {
    const int rowBase = tile << 6;
    __syncthreads();   // prior tile's LDS reads done (and W ready on first iter)

    if (g.inBf16) {
      const unsigned short* Ab = (const unsigned short*)g.A;
      #pragma unroll
      for (int it = 0; it < 4; ++it) {
        int i8 = t + it * 256;
        int byteoff = i8 << 4;
        int r = byteoff >> 8;
        int gr = rowBase + r; if (gr >= g.M) gr = g.M - 1;
        u16x8 h = *(const u16x8*)((const char*)Ab + (size_t)gr * 256 + (byteoff & 255));
        *(u16x8*)((char*)As + (byteoff ^ ((r & 7) << 4))) = h;
      }
    } else {
      const float* Af = (const float*)g.A;
      #pragma unroll
      for (int it = 0; it < 4; ++it) {
        int i8 = t + it * 256;
        int byteoff = i8 << 4;               // 16B of bf16 out = 8 floats in
        int r = byteoff >> 8;
        int gr = rowBase + r; if (gr >= g.M) gr = g.M - 1;
        int fo = (byteoff & 255) >> 1;       // float offset in row
        float4 v0 = *(const float4*)(Af + (size_t)gr * HD + fo);
        float4 v1 = *(const float4*)(Af + (size_t)gr * HD + fo + 4);
        u16x8 h;
        h[0] = f2bf(v0.x); h[1] = f2bf(v0.y); h[2] = f2bf(v0.z); h[3] = f2bf(v0.w);
        h[4] = f2bf(v1.x); h[5] = f2bf(v1.y); h[6] = f2bf(v1.z); h[7] = f2bf(v1.w);
        *(u16x8*)((char*)As + (byteoff ^ ((r & 7) << 4))) = h;
      }
    }
    __syncthreads();

    bf16x8 afr[4];
    #pragma unroll
    for (int kc = 0; kc < 4; ++kc) {
      int r = wv * 16 + lr;
      int byte = r * 256 + kc * 64 + lk * 16;
      afr[kc] = *(const bf16x8*)((char*)As + (byte ^ ((r & 7) << 4)));
    }

    f32x4 acc[8];
    #pragma unroll
    for (int nt = 0; nt < 8; ++nt) acc[nt] = (f32x4){0.f, 0.f, 0.f, 0.f};

    #pragma unroll
    for (int nt = 0; nt < 8; ++nt) {
      int n = nt * 16 + lr;
      int nbyte = n * 256 + lk * 16;
      int nswz = (n & 7) << 4;
      #pragma unroll
      for (int kc = 0; kc < 4; ++kc) {
        bf16x8 bfr = *(const bf16x8*)((char*)Wsm + ((nbyte + kc * 64) ^ nswz));
        acc[nt] = __builtin_amdgcn_mfma_f32_16x16x32_bf16(afr[kc], bfr, acc[nt], 0, 0, 0);
      }
    }

    #pragma unroll
    for (int nt = 0; nt < 8; ++nt) {
      int col = nt * 16 + lr;
      float bv = g.bias ? g.bias[col] : 0.f;
      #pragma unroll
      for (int q = 0; q < 4; ++q) {
        int grow = rowBase + wv * 16 + lk * 4 + q;
        if (grow < g.M) {
          float val = acc[nt][q] + bv;
          if (g.outBf16) ((unsigned short*)g.C)[(size_t)grow * HD + col] = f2bf(val);
          else           ((float*)g.C)[(size_t)grow * HD + col] = val;
        }
      }
    }
  }
}

// ---------------- grouped gather v2: 16-lane group per row ----------------
// out[row] = relu(T_init[row] + sum_j mean_{src in seg_j} T_j[src])
struct GGatArgs {
  const unsigned short* T;   // group T arena (init at rows [0,n))
  const int* rp;             // global rowptr
  const int* col;            // global col (src)
  void* outp;                // bf16 (L1) or f32 (L2)
  int n, nrel, outBf16;
  int rpOff[6];
  int tOff[6];
};

__global__ __launch_bounds__(256) void ggather_kernel(GGatArgs g) {
  int wid = (blockIdx.x * 256 + threadIdx.x) >> 4;   // one 16-lane group per row
  int cl  = threadIdx.x & 15;                        // covers elems [cl*8, cl*8+8)
  if (wid >= g.n) return;
  float acc[8], acc2[8];
  #pragma unroll
  for (int k = 0; k < 8; ++k) { acc[k] = 0.f; acc2[k] = 0.f; }

  #pragma unroll
  for (int j = 0; j < 6; ++j) {
    if (j < g.nrel) {
      int base = g.rpOff[j] + wid;
      int s = g.rp[base], e = g.rp[base + 1];
      if (s < e) {
        float inv = 1.f / (float)(e - s);
        const unsigned short* Tj = g.T + ((size_t)g.tOff[j] << 7);
        int i = s;
        for (; i + 1 < e; i += 2) {
          int s0 = g.col[i], s1 = g.col[i + 1];
          u16x8 v0 = *(const u16x8*)(Tj + ((size_t)s0 << 7) + cl * 8);
          u16x8 v1 = *(const u16x8*)(Tj + ((size_t)s1 << 7) + cl * 8);
          #pragma unroll
          for (int k = 0; k < 8; ++k) {
            acc[k]  = fmaf(bf2f(v0[k]), inv, acc[k]);
            acc2[k] = fmaf(bf2f(v1[k]), inv, acc2[k]);
          }
        }
        if (i < e) {
          int s0 = g.col[i];
          u16x8 v0 = *(const u16x8*)(Tj + ((size_t)s0 << 7) + cl * 8);
          #pragma unroll
          for (int k = 0; k < 8; ++k) acc[k] = fmaf(bf2f(v0[k]), inv, acc[k]);
        }
      }
    }
  }

  u16x8 iv = *(const u16x8*)(g.T + ((size_t)wid << 7) + cl * 8);
  if (g.outBf16) {
    u16x8 o;
    #pragma unroll
    for (int k = 0; k < 8; ++k)
      o[k] = f2bf(fmaxf(acc[k] + acc2[k] + bf2f(iv[k]), 0.f));
    *(u16x8*)((unsigned short*)g.outp + ((size_t)wid << 7) + cl * 8) = o;
  } else {
    float* op = (float*)g.outp + ((size_t)wid << 7) + cl * 8;
    float v[8];
    #pragma unroll
    for (int k = 0; k < 8; ++k) v[k] = fmaxf(acc[k] + acc2[k] + bf2f(iv[k]), 0.f);
    *(float4*)op       = make_float4(v[0], v[1], v[2], v[3]);
    *(float4*)(op + 4) = make_float4(v[4], v[5], v[6], v[7]);
  }
}

// ---------------- final: out[M x 64] = X[M x 128] @ W[128 x 64] + b ----------------
struct FinalArgs { const float* X; const float* W; const float* b; float* out; int M; };

__global__ __launch_bounds__(256) void final_kernel(FinalArgs f) {
  __shared__ float xs[512];
  int t = threadIdx.x;
  int row0 = blockIdx.x << 2;
  {
    int li = t << 1;
    int lrow = li >> 7;
    float2 v = make_float2(0.f, 0.f);
    if (row0 + lrow < f.M) v = *(const float2*)(f.X + (size_t)(row0 + lrow) * HD + (li & 127));
    *(float2*)(&xs[li]) = v;
  }
  __syncthreads();
  int r = t >> 6, c = t & 63;
  float acc = 0.f;
  const float* xrow = &xs[r << 7];
  #pragma unroll 8
  for (int k = 0; k < HD; ++k) acc = fmaf(xrow[k], f.W[k * 64 + c], acc);
  if (row0 + r < f.M) f.out[(size_t)(row0 + r) * 64 + c] = acc + f.b[c];
}

// ---------------- host ----------------
extern "C" void kernel_launch(void* const* d_in, const int* in_sizes, int n_in,
                              void* d_out, int out_size, void* d_ws, size_t ws_size,
                              hipStream_t stream) {
  static const int NODESN[10] = {50000, 2000, 80000, 10000, 2000, 150000, 120000, 100000, 60000, 40000};
  static const int FWD_S[13] = {0, 0, 0, 0, 0, 0, 6, 5, 5, 4, 4, 2, 2};
  static const int FWD_D[13] = {1, 2, 3, 4, 5, 6, 7, 6, 7, 5, 3, 8, 9};
  static const int ACT1[22] = {0,1,2,3,4,5,6,7,8,9,10,11,13,14,15,17,18,19,20,21,23,25};
  // relations grouped by dst type (course, field, resource, teacher, school, user, comment):
  static const int GRPREL[22] = {1,3,5,7,9,11,  0,  2,23,25,  4,20,  6,19,21,  8,15,17,18,  10,13,14};
  static const int GN[7]    = {6, 1, 3, 2, 3, 4, 3};
  static const int GBASE[7] = {0, 6, 7, 10, 12, 15, 19};
  static const int AOFF[7]  = {0, 50000, 52000, 132000, 142000, 144000, 294000};

  // workspace layout (floats) — total ~307.2 MB (< round-3's 323.0 MB known fit)
  float* ws = (float*)d_ws;
  size_t offA    = 0;                                  // 414000*128 bf16 = 26,496,000 f
  size_t offB    = offA + 26496000;                    // 50000*128 f32
  size_t offT    = offB + 6400000;                     // 422000*128 bf16 = 27,008,000 f
  size_t offCnt  = offT + 27008000;                    // NROWS ints
  size_t offRp   = offCnt + NROWS;                     // NROWS+1 ints
  size_t offCol  = offRp + NROWS + 1;                  // NEDGE ints
  size_t offBkt  = offCol + NEDGE;                     // NEDGE u32
  size_t offBCnt = offBkt + NEDGE;                     // 22*NB ints
  size_t offBRp  = offBCnt + 22 * NB;                  // 22*NB+1 ints
  size_t offBCur = offBRp + 22 * NB + 4;               // 22*NB ints
  size_t offBs   = offBCur + 22 * NB;                  // 1024 ints
  size_t offWrS  = offBs + 1024;                       // 20*16384 f32
  size_t offBlS  = offWrS + (size_t)20 * 16384;        // 20*128 f32
  size_t offWt   = offBlS + (size_t)20 * HD;           // 36*16384 bf16 = 294,912 f
  size_t needFloats = offWt + 294912;
  if (ws_size < needFloats * sizeof(float)) return;

  const float* x_in[10];
  for (int t = 0; t < 10; ++t) x_in[t] = (const float*)d_in[t];
  const int* ei[13];
  for (int k = 0; k < 13; ++k) ei[k] = (const int*)d_in[10 + k];
  const float* Wl   = (const float*)d_in[23];
  const float* bl   = (const float*)d_in[24];
  const float* Wr   = (const float*)d_in[25];
  const float* linW = (const float*)d_in[26];
  const float* linb = (const float*)d_in[27];
  float* out = (float*)d_out;

  unsigned short* A  = (unsigned short*)(ws + offA);
  float*          B  = ws + offB;
  unsigned short* T  = (unsigned short*)(ws + offT);
  int* cnt  = (int*)(ws + offCnt);
  int* rp   = (int*)(ws + offRp);
  int* col  = (int*)(ws + offCol);
  unsigned* bkt = (unsigned*)(ws + offBkt);
  int* bCnt = (int*)(ws + offBCnt);
  int* bRp  = (int*)(ws + offBRp);
  int* bCur = (int*)(ws + offBCur);
  int* bs   = (int*)(ws + offBs);
  unsigned short* wt = (unsigned short*)(ws + offWt);

  auto relSrc = [&](int r) { int k = r >> 1; return (r & 1) ? FWD_D[k] : FWD_S[k]; };
  auto relDst = [&](int r) { int k = r >> 1; return (r & 1) ? FWD_S[k] : FWD_D[k]; };

  // host tables
  int segOff[22], shiftv[22], nDstv[22];
  { int acc = 0;
    for (int i = 0; i < 22; ++i) {
      int nd = NODESN[relDst(GRPREL[i])];
      segOff[i] = acc; acc += nd;
      nDstv[i] = nd;
      int s = 0; while (((nd + (1 << s) - 1) >> s) > NB) ++s;
      shiftv[i] = s;
    }
  }
  int wtSlot[26];
  for (int r = 0; r < 26; ++r) wtSlot[r] = -1;
  for (int i = 0; i < 22; ++i) wtSlot[ACT1[i]] = i;

  // 1. WrSum / blSum
  WSumArgs wa{};
  wa.Wr = Wr; wa.bl = bl; wa.WrSum = ws + offWrS; wa.blSum = ws + offBlS;
  for (int l = 0; l < 2; ++l)
    for (int t = 0; t < 10; ++t) wa.mask[l][t] = 0;
  for (int r = 0; r < 26; ++r) { int d = relDst(r); if (d <= 6) wa.mask[0][d] |= 1u << r; }
  for (int j = 0; j < 6; ++j) wa.mask[1][0] |= 1u << GRPREL[j];
  wsum_kernel<<<1280, 256, 0, stream>>>(wa);

  // 2. weight table
  WtPrepArgs wp{};
  wp.Wl = Wl; wp.WrSum = ws + offWrS; wp.wt = wt;
  for (int i = 0; i < 22; ++i) wp.code[i] = ACT1[i];
  for (int j = 0; j < 6; ++j)  wp.code[22 + j] = 26 + GRPREL[j];
  for (int d = 0; d < 7; ++d)  wp.code[28 + d] = 100 + d;
  wp.code[35] = 100 + 10;
  wtprep_kernel<<<36 * 16, 256, 0, stream>>>(wp);

  // 3. bucketed CSR build
  hipMemsetAsync(bCnt, 0, (size_t)22 * NB * sizeof(int), stream);
  BktArgs ka{};
  for (int k = 0; k < 13; ++k) ka.ei[k] = ei[k];
  ka.bkt = bkt; ka.bktCnt = bCnt; ka.bktCur = bCur;
  for (int i = 0; i < 22; ++i) { ka.rel[i] = GRPREL[i]; ka.shiftv[i] = shiftv[i]; }
  bktcount_kernel<<<22 * AWG, 256, 0, stream>>>(ka);
  scan_blk<<<2, 256, 0, stream>>>(bCnt, bRp, bs, 22 * NB);
  scan_top<<<1, 1024, 0, stream>>>(bs, 2);
  scan_add<<<(22 * NB + 255) / 256, 256, 0, stream>>>(bRp, bCur, bs, 22 * NB, NEDGE);
  bktfill_kernel<<<22 * AWG, 256, 0, stream>>>(ka);
  PlaceArgs pa{};
  pa.bkt = bkt; pa.bktRp = bRp; pa.cntG = cnt; pa.rp = rp; pa.col = col;
  for (int i = 0; i < 22; ++i) { pa.segOff[i] = segOff[i]; pa.shiftv[i] = shiftv[i]; pa.nDst[i] = nDstv[i]; }
  rowcount_kernel<<<22 * NB, 256, 0, stream>>>(pa);
  int nblk = (NROWS + 2047) / 2048;   // 747
  scan_blk<<<nblk, 256, 0, stream>>>(cnt, rp, bs, NROWS);
  scan_top<<<1, 1024, 0, stream>>>(bs, nblk);
  scan_add<<<(NROWS + 255) / 256, 256, 0, stream>>>(rp, cnt, bs, NROWS, NEDGE);
  place_kernel<<<22 * NB, 256, 0, stream>>>(pa);

  auto mgemmGrid = [&](int M) { int tl = (M + 63) / 64; return tl < 512 ? tl : 512; };

  // 4. layer 1, grouped by dst type
  for (int d = 0; d < 7; ++d) {
    int nd = NODESN[d];
    MGemmArgs gi{(const void*)x_in[d], wt + ((size_t)(28 + d) << 14),
                 ws + offBlS + (size_t)d * HD, (void*)T, nd, 1, 0};
    mgemm_kernel<<<mgemmGrid(nd), 256, 0, stream>>>(gi);
    GGatArgs ga{};
    ga.T = T; ga.rp = rp; ga.col = col;
    ga.outp = (void*)(A + (size_t)AOFF[d] * HD);
    ga.n = nd; ga.nrel = GN[d]; ga.outBf16 = 1;
    int toff = nd;
    for (int j = 0; j < GN[d]; ++j) {
      int r = GRPREL[GBASE[d] + j];
      int s = relSrc(r);
      MGemmArgs g{(const void*)x_in[s], wt + ((size_t)wtSlot[r] << 14), nullptr,
                  (void*)(T + (size_t)toff * HD), NODESN[s], 1, 0};
      mgemm_kernel<<<mgemmGrid(NODESN[s]), 256, 0, stream>>>(g);
      ga.rpOff[j] = segOff[GBASE[d] + j];
      ga.tOff[j] = toff;
      toff += NODESN[s];
    }
    ggather_kernel<<<(nd + 15) / 16, 256, 0, stream>>>(ga);
  }

  // 5. layer 2 (course only; same CSR segments as group 0, inputs from bf16 A)
  {
    MGemmArgs gi{(const void*)A, wt + ((size_t)35 << 14),
                 ws + offBlS + (size_t)10 * HD, (void*)T, 50000, 1, 1};
    mgemm_kernel<<<mgemmGrid(50000), 256, 0, stream>>>(gi);
    GGatArgs ga{};
    ga.T = T; ga.rp = rp; ga.col = col;
    ga.outp = (void*)B;
    ga.n = 50000; ga.nrel = 6; ga.outBf16 = 0;
    int toff = 50000;
    for (int j = 0; j < 6; ++j) {
      int r = GRPREL[j];
      int s = relSrc(r);
      MGemmArgs g{(const void*)(A + (size_t)AOFF[s] * HD), wt + ((size_t)(22 + j) << 14),
                  nullptr, (void*)(T + (size_t)toff * HD), NODESN[s], 1, 1};
      mgemm_kernel<<<mgemmGrid(NODESN[s]), 256, 0, stream>>>(g);
      ga.rpOff[j] = segOff[j];
      ga.tOff[j] = toff;
      toff += NODESN[s];
    }
    ggather_kernel<<<(50000 + 15) / 16, 256, 0, stream>>>(ga);
  }

  // 6. final linear
  FinalArgs fa{B, linW, linb, out, 50000};
  final_kernel<<<12500, 256, 0, stream>>>(fa);
}

// Round 11
// 1370.315 us; speedup vs baseline: 1.1143x; 1.1143x over previous
//
#include <hip/hip_runtime.h>
#include <stdint.h>

#define HD 128
#define EE 300000
#define NROWS 1528000   // sum n_dst over 22 active relations (grouped by dst)
#define NEDGE 6600000   // 22 * EE
#define NB 128          // buckets per relation
#define ATILE 4096      // edges per bucketing workgroup
#define AWG 74          // ceil(EE / ATILE)

typedef __attribute__((ext_vector_type(8))) short bf16x8;
typedef __attribute__((ext_vector_type(4))) float f32x4;
typedef __attribute__((ext_vector_type(8))) unsigned short u16x8;

static __device__ __forceinline__ unsigned short f2bf(float x) {
  union { float f; unsigned u; } v; v.f = x;
  unsigned r = v.u + 0x7FFFu + ((v.u >> 16) & 1u);
  return (unsigned short)(r >> 16);
}
static __device__ __forceinline__ float bf2f(unsigned short h) {
  union { unsigned u; float f; } v; v.u = ((unsigned)h) << 16;
  return v.f;
}

// ---------------- weight pre-sum (WrSum per (layer,type), blSum) ----------------
struct WSumArgs {
  const float* Wr;   // [2][26][128][128]
  const float* bl;   // [2][26][128]
  float* WrSum;      // [2][10][128][128]
  float* blSum;      // [2][10][128]
  unsigned int mask[2][10];
};

__global__ __launch_bounds__(256) void wsum_kernel(WSumArgs a) {
  int lt  = blockIdx.x >> 6;
  int blk = blockIdx.x & 63;
  int layer = lt / 10, type = lt % 10;
  unsigned m = a.mask[layer][type];
  int idx = blk * 256 + threadIdx.x;   // 0..16383
  float s = 0.f;
  for (int r = 0; r < 26; ++r)
    if (m & (1u << r)) s += a.Wr[((size_t)(layer * 26 + r) << 14) + idx];
  a.WrSum[((size_t)(layer * 10 + type) << 14) + idx] = s;
  if (idx < HD) {
    float b = 0.f;
    for (int r = 0; r < 26; ++r)
      if (m & (1u << r)) b += a.bl[(size_t)(layer * 26 + r) * HD + idx];
    a.blSum[(size_t)(layer * 10 + type) * HD + idx] = b;
  }
}

// ---------------- weight transpose+bf16 prep: wt[m][n][k] = bf16(src[m][k][n]) ----------------
struct WtPrepArgs {
  const float* Wl;     // [52][128][128]
  const float* WrSum;  // [20][128][128]
  unsigned short* wt;  // [36][128][128] (n-major, k contiguous)
  int code[36];        // <100: Wl flat index; >=100: WrSum flat index - 100
};

__global__ __launch_bounds__(256) void wtprep_kernel(WtPrepArgs a) {
  int m = blockIdx.x >> 4;
  int chunk = blockIdx.x & 15;
  int idx = chunk * 256 + threadIdx.x;   // float4 index 0..4095
  int c = a.code[m];
  const float* src = (c < 100) ? a.Wl + ((size_t)c << 14)
                               : a.WrSum + ((size_t)(c - 100) << 14);
  int k = idx >> 5, n0 = (idx & 31) << 2;
  float4 v = *(const float4*)(src + (size_t)k * HD + n0);
  unsigned short* d = a.wt + ((size_t)m << 14);
  d[(size_t)(n0 + 0) * HD + k] = f2bf(v.x);
  d[(size_t)(n0 + 1) * HD + k] = f2bf(v.y);
  d[(size_t)(n0 + 2) * HD + k] = f2bf(v.z);
  d[(size_t)(n0 + 3) * HD + k] = f2bf(v.w);
}

// ---------------- bucketed CSR build ----------------
struct BktArgs {
  const int* ei[13];
  unsigned* bkt;     // [NEDGE] packed entries (dstlow<<18)|src
  int* bktCnt;       // [22*NB]
  int* bktCur;       // [22*NB]
  int rel[22];
  int shiftv[22];
};

__global__ __launch_bounds__(256) void bktcount_kernel(BktArgs a) {
  __shared__ int cnt[NB];
  int ri = blockIdx.x / AWG;
  int tile = (blockIdx.x % AWG) * ATILE;
  int t = threadIdx.x;
  if (t < NB) cnt[t] = 0;
  __syncthreads();
  int r = a.rel[ri];
  const int* ei = a.ei[r >> 1];
  int flip = r & 1, sh = a.shiftv[ri];
  #pragma unroll
  for (int j = 0; j < 16; ++j) {
    int e = tile + j * 256 + t;
    if (e < EE) {
      int dst = flip ? ei[e] : ei[EE + e];
      atomicAdd(&cnt[dst >> sh], 1);
    }
  }
  __syncthreads();
  if (t < NB && cnt[t]) atomicAdd(&a.bktCnt[ri * NB + t], cnt[t]);
}

__global__ __launch_bounds__(256) void bktfill_kernel(BktArgs a) {
  __shared__ int cnt[NB];
  __shared__ int base[NB];
  int ri = blockIdx.x / AWG;
  int tile = (blockIdx.x % AWG) * ATILE;
  int t = threadIdx.x;
  if (t < NB) cnt[t] = 0;
  __syncthreads();
  int r = a.rel[ri];
  const int* ei = a.ei[r >> 1];
  int flip = r & 1, sh = a.shiftv[ri];
  unsigned mask = (1u << sh) - 1u;
  unsigned pj[16]; int bj[16];
  #pragma unroll
  for (int j = 0; j < 16; ++j) {
    int e = tile + j * 256 + t;
    if (e < EE) {
      int src = flip ? ei[EE + e] : ei[e];
      int dst = flip ? ei[e] : ei[EE + e];
      int b = dst >> sh;
      pj[j] = (((unsigned)dst & mask) << 18) | (unsigned)src;
      bj[j] = b;
      atomicAdd(&cnt[b], 1);
    } else bj[j] = -1;
  }
  __syncthreads();
  if (t < NB) base[t] = cnt[t] ? atomicAdd(&a.bktCur[ri * NB + t], cnt[t]) : 0;
  __syncthreads();
  if (t < NB) cnt[t] = base[t];
  __syncthreads();
  #pragma unroll
  for (int j = 0; j < 16; ++j) {
    if (bj[j] >= 0) {
      int pos = atomicAdd(&cnt[bj[j]], 1);
      a.bkt[pos] = pj[j];
    }
  }
}

struct PlaceArgs {
  const unsigned* bkt;
  const int* bktRp;   // [22*NB+1]
  int* cntG;          // [NROWS]
  const int* rp;      // [NROWS+1]
  int* col;           // [NEDGE]
  int segOff[22];
  int shiftv[22];
  int nDst[22];
};

__global__ __launch_bounds__(256) void rowcount_kernel(PlaceArgs a) {
  __shared__ int cnt[2048];
  int bx = blockIdx.x;
  int ri = bx >> 7, b = bx & (NB - 1);
  int sh = a.shiftv[ri], nd = a.nDst[ri];
  int rowLo = b << sh;
  if (rowLo >= nd) return;
  int rows = min(1 << sh, nd - rowLo);
  int t = threadIdx.x;
  for (int k = t; k < rows; k += 256) cnt[k] = 0;
  __syncthreads();
  int s = a.bktRp[bx], e = a.bktRp[bx + 1];
  for (int i = s + t; i < e; i += 256) atomicAdd(&cnt[a.bkt[i] >> 18], 1);
  __syncthreads();
  int rowBase = a.segOff[ri] + rowLo;
  for (int k = t; k < rows; k += 256) a.cntG[rowBase + k] = cnt[k];
}

__global__ __launch_bounds__(256) void place_kernel(PlaceArgs a) {
  __shared__ int cur[2048];
  int bx = blockIdx.x;
  int ri = bx >> 7, b = bx & (NB - 1);
  int sh = a.shiftv[ri], nd = a.nDst[ri];
  int rowLo = b << sh;
  if (rowLo >= nd) return;
  int rows = min(1 << sh, nd - rowLo);
  int t = threadIdx.x;
  int rowBase = a.segOff[ri] + rowLo;
  for (int k = t; k < rows; k += 256) cur[k] = a.rp[rowBase + k];
  __syncthreads();
  int s = a.bktRp[bx], e = a.bktRp[bx + 1];
  for (int i = s + t; i < e; i += 256) {
    unsigned u = a.bkt[i];
    int pos = atomicAdd(&cur[u >> 18], 1);
    a.col[pos] = (int)(u & 0x3FFFFu);
  }
}

// ---------------- scans ----------------
__global__ __launch_bounds__(256) void scan_blk(const int* cnt, int* rp, int* bsum, int n) {
  __shared__ int sh[256];
  int t = threadIdx.x;
  int base = blockIdx.x * 2048 + t * 8;
  int v[8]; int s = 0;
  #pragma unroll
  for (int j = 0; j < 8; ++j) { int idx = base + j; v[j] = (idx < n) ? cnt[idx] : 0; s += v[j]; }
  sh[t] = s; __syncthreads();
  for (int d = 1; d < 256; d <<= 1) {
    int x = (t >= d) ? sh[t - d] : 0;
    __syncthreads();
    sh[t] += x;
    __syncthreads();
  }
  int excl = sh[t] - s;
  if (t == 255) bsum[blockIdx.x] = sh[255];
  int run = excl;
  #pragma unroll
  for (int j = 0; j < 8; ++j) { int idx = base + j; if (idx < n) rp[idx] = run; run += v[j]; }
}

__global__ __launch_bounds__(1024) void scan_top(int* bsum, int nb) {
  __shared__ int sh[1024];
  int t = threadIdx.x;
  int s = (t < nb) ? bsum[t] : 0;
  sh[t] = s; __syncthreads();
  for (int d = 1; d < 1024; d <<= 1) {
    int x = (t >= d) ? sh[t - d] : 0;
    __syncthreads();
    sh[t] += x;
    __syncthreads();
  }
  if (t < nb) bsum[t] = sh[t] - s;
}

__global__ __launch_bounds__(256) void scan_add(int* rp, int* cur, const int* bsum, int n, int total) {
  int i = blockIdx.x * 256 + threadIdx.x;
  if (i < n) { int v = rp[i] + bsum[i >> 11]; rp[i] = v; cur[i] = v; }
  if (i == 0) rp[n] = total;
}

// ---------------- bf16 MFMA GEMM (W-resident grid-stride) ----------------
struct MGemmArgs { const void* A; const unsigned short* Wt; const float* bias; void* C;
                   int M; int outBf16; int inBf16; };

__global__ __launch_bounds__(256) void mgemm_kernel(MGemmArgs g) {
  __shared__ unsigned short As[64 * HD];   // [r][k] bf16, byte ^ ((r&7)<<4)
  __shared__ unsigned short Wsm[HD * HD];  // [n][k] bf16, byte ^ ((n&7)<<4)
  const int t = threadIdx.x;

  // stage W once (8 x 16B per thread)
  #pragma unroll
  for (int it = 0; it < 8; ++it) {
    int i8 = t + it * 256;
    int byteoff = i8 << 4;
    int n = byteoff >> 8;
    u16x8 w = *(const u16x8*)((const char*)g.Wt + byteoff);
    *(u16x8*)((char*)Wsm + (byteoff ^ ((n & 7) << 4))) = w;
  }

  const int wv = t >> 6;
  const int lane = t & 63;
  const int lr = lane & 15;
  const int lk = lane >> 4;
  const int tiles = (g.M + 63) >> 6;

  for (int tile = blockIdx.x; tile < tiles; tile += gridDim.x) {
    const int rowBase = tile << 6;
    __syncthreads();

    if (g.inBf16) {
      const unsigned short* Ab = (const unsigned short*)g.A;
      #pragma unroll
      for (int it = 0; it < 4; ++it) {
        int i8 = t + it * 256;
        int byteoff = i8 << 4;
        int r = byteoff >> 8;
        int gr = rowBase + r; if (gr >= g.M) gr = g.M - 1;
        u16x8 h = *(const u16x8*)((const char*)Ab + (size_t)gr * 256 + (byteoff & 255));
        *(u16x8*)((char*)As + (byteoff ^ ((r & 7) << 4))) = h;
      }
    } else {
      const float* Af = (const float*)g.A;
      #pragma unroll
      for (int it = 0; it < 4; ++it) {
        int i8 = t + it * 256;
        int byteoff = i8 << 4;
        int r = byteoff >> 8;
        int gr = rowBase + r; if (gr >= g.M) gr = g.M - 1;
        int fo = (byteoff & 255) >> 1;
        float4 v0 = *(const float4*)(Af + (size_t)gr * HD + fo);
        float4 v1 = *(const float4*)(Af + (size_t)gr * HD + fo + 4);
        u16x8 h;
        h[0] = f2bf(v0.x); h[1] = f2bf(v0.y); h[2] = f2bf(v0.z); h[3] = f2bf(v0.w);
        h[4] = f2bf(v1.x); h[5] = f2bf(v1.y); h[6] = f2bf(v1.z); h[7] = f2bf(v1.w);
        *(u16x8*)((char*)As + (byteoff ^ ((r & 7) << 4))) = h;
      }
    }
    __syncthreads();

    bf16x8 afr[4];
    #pragma unroll
    for (int kc = 0; kc < 4; ++kc) {
      int r = wv * 16 + lr;
      int byte = r * 256 + kc * 64 + lk * 16;
      afr[kc] = *(const bf16x8*)((char*)As + (byte ^ ((r & 7) << 4)));
    }

    f32x4 acc[8];
    #pragma unroll
    for (int nt = 0; nt < 8; ++nt) acc[nt] = (f32x4){0.f, 0.f, 0.f, 0.f};

    #pragma unroll
    for (int nt = 0; nt < 8; ++nt) {
      int n = nt * 16 + lr;
      int nbyte = n * 256 + lk * 16;
      int nswz = (n & 7) << 4;
      #pragma unroll
      for (int kc = 0; kc < 4; ++kc) {
        bf16x8 bfr = *(const bf16x8*)((char*)Wsm + ((nbyte + kc * 64) ^ nswz));
        acc[nt] = __builtin_amdgcn_mfma_f32_16x16x32_bf16(afr[kc], bfr, acc[nt], 0, 0, 0);
      }
    }

    #pragma unroll
    for (int nt = 0; nt < 8; ++nt) {
      int col = nt * 16 + lr;
      float bv = g.bias ? g.bias[col] : 0.f;
      #pragma unroll
      for (int q = 0; q < 4; ++q) {
        int grow = rowBase + wv * 16 + lk * 4 + q;
        if (grow < g.M) {
          float val = acc[nt][q] + bv;
          if (g.outBf16) ((unsigned short*)g.C)[(size_t)grow * HD + col] = f2bf(val);
          else           ((float*)g.C)[(size_t)grow * HD + col] = val;
        }
      }
    }
  }
}

// ---------------- grouped gather v3: degree-adaptive lanes-per-row ----------------
// gsize = 16*npar lanes per row (npar in {1,4,16}); npar sub-groups stride neighbors.
// out[row] = relu(T_init[row] + sum_j mean_{src in seg_j} T_j[src])
struct GGatArgs {
  const unsigned short* T;   // group T arena (init at rows [0,n))
  const int* rp;             // global rowptr
  const int* col;            // global col (src)
  void* outp;                // bf16 (L1) or f32 (L2)
  int n, nrel, outBf16, lgG; // lgG = log2(gsize) in {4,6,8}
  int rpOff[6];
  int tOff[6];
};

__global__ __launch_bounds__(256) void ggather_kernel(GGatArgs g) {
  __shared__ float red[3][128];
  const int gsize = 1 << g.lgG;
  const int npar = gsize >> 4;
  const int gid = (int)((blockIdx.x * 256 + threadIdx.x) >> g.lgG);
  const int within = threadIdx.x & (gsize - 1);
  const int p = within >> 4;
  const int cl = within & 15;
  const bool active = gid < g.n;

  float acc[8], acc2[8];
  #pragma unroll
  for (int k = 0; k < 8; ++k) { acc[k] = 0.f; acc2[k] = 0.f; }

  if (active) {
    #pragma unroll
    for (int j = 0; j < 6; ++j) {
      if (j < g.nrel) {
        int base = g.rpOff[j] + gid;
        int s = g.rp[base], e = g.rp[base + 1];
        if (s < e) {
          float inv = 1.f / (float)(e - s);
          const unsigned short* Tj = g.T + ((size_t)g.tOff[j] << 7);
          int i = s + p;
          for (; i + npar < e; i += 2 * npar) {
            int s0 = g.col[i], s1 = g.col[i + npar];
            u16x8 v0 = *(const u16x8*)(Tj + ((size_t)s0 << 7) + cl * 8);
            u16x8 v1 = *(const u16x8*)(Tj + ((size_t)s1 << 7) + cl * 8);
            #pragma unroll
            for (int k = 0; k < 8; ++k) {
              acc[k]  = fmaf(bf2f(v0[k]), inv, acc[k]);
              acc2[k] = fmaf(bf2f(v1[k]), inv, acc2[k]);
            }
          }
          if (i < e) {
            int s0 = g.col[i];
            u16x8 v0 = *(const u16x8*)(Tj + ((size_t)s0 << 7) + cl * 8);
            #pragma unroll
            for (int k = 0; k < 8; ++k) acc[k] = fmaf(bf2f(v0[k]), inv, acc[k]);
          }
        }
      }
    }
  }
  #pragma unroll
  for (int k = 0; k < 8; ++k) acc[k] += acc2[k];

  if (npar > 1) {
    // collapse the (up to 4) sub-groups within each wave
    #pragma unroll
    for (int k = 0; k < 8; ++k) {
      acc[k] += __shfl_xor(acc[k], 16);
      acc[k] += __shfl_xor(acc[k], 32);
    }
    if (gsize == 256) {
      // cross-wave reduce: block == one row; always fully active (grid = n)
      int wvi = threadIdx.x >> 6;
      if (wvi > 0 && (threadIdx.x & 63) < 16) {
        #pragma unroll
        for (int k = 0; k < 8; ++k) red[wvi - 1][cl * 8 + k] = acc[k];
      }
      __syncthreads();
      if (threadIdx.x < 16) {
        #pragma unroll
        for (int k = 0; k < 8; ++k)
          acc[k] += red[0][cl * 8 + k] + red[1][cl * 8 + k] + red[2][cl * 8 + k];
      }
    }
  }

  if (active && within < 16) {
    u16x8 iv = *(const u16x8*)(g.T + ((size_t)gid << 7) + cl * 8);
    if (g.outBf16) {
      u16x8 o;
      #pragma unroll
      for (int k = 0; k < 8; ++k)
        o[k] = f2bf(fmaxf(acc[k] + bf2f(iv[k]), 0.f));
      *(u16x8*)((unsigned short*)g.outp + ((size_t)gid << 7) + cl * 8) = o;
    } else {
      float* op = (float*)g.outp + ((size_t)gid << 7) + cl * 8;
      float v[8];
      #pragma unroll
      for (int k = 0; k < 8; ++k) v[k] = fmaxf(acc[k] + bf2f(iv[k]), 0.f);
      *(float4*)op       = make_float4(v[0], v[1], v[2], v[3]);
      *(float4*)(op + 4) = make_float4(v[4], v[5], v[6], v[7]);
    }
  }
}

// ---------------- final: out[M x 64] = X[M x 128] @ W[128 x 64] + b ----------------
struct FinalArgs { const float* X; const float* W; const float* b; float* out; int M; };

__global__ __launch_bounds__(256) void final_kernel(FinalArgs f) {
  __shared__ float xs[512];
  int t = threadIdx.x;
  int row0 = blockIdx.x << 2;
  {
    int li = t << 1;
    int lrow = li >> 7;
    float2 v = make_float2(0.f, 0.f);
    if (row0 + lrow < f.M) v = *(const float2*)(f.X + (size_t)(row0 + lrow) * HD + (li & 127));
    *(float2*)(&xs[li]) = v;
  }
  __syncthreads();
  int r = t >> 6, c = t & 63;
  float acc = 0.f;
  const float* xrow = &xs[r << 7];
  #pragma unroll 8
  for (int k = 0; k < HD; ++k) acc = fmaf(xrow[k], f.W[k * 64 + c], acc);
  if (row0 + r < f.M) f.out[(size_t)(row0 + r) * 64 + c] = acc + f.b[c];
}

// ---------------- host ----------------
extern "C" void kernel_launch(void* const* d_in, const int* in_sizes, int n_in,
                              void* d_out, int out_size, void* d_ws, size_t ws_size,
                              hipStream_t stream) {
  static const int NODESN[10] = {50000, 2000, 80000, 10000, 2000, 150000, 120000, 100000, 60000, 40000};
  static const int FWD_S[13] = {0, 0, 0, 0, 0, 0, 6, 5, 5, 4, 4, 2, 2};
  static const int FWD_D[13] = {1, 2, 3, 4, 5, 6, 7, 6, 7, 5, 3, 8, 9};
  static const int ACT1[22] = {0,1,2,3,4,5,6,7,8,9,10,11,13,14,15,17,18,19,20,21,23,25};
  // relations grouped by dst type (course, field, resource, teacher, school, user, comment):
  static const int GRPREL[22] = {1,3,5,7,9,11,  0,  2,23,25,  4,20,  6,19,21,  8,15,17,18,  10,13,14};
  static const int GN[7]    = {6, 1, 3, 2, 3, 4, 3};
  static const int GBASE[7] = {0, 6, 7, 10, 12, 15, 19};
  static const int AOFF[7]  = {0, 50000, 52000, 132000, 142000, 144000, 294000};
  // lanes-per-row = 1<<GLG, chosen from sum-of-degrees per row:
  // course 36 -> 64; field 150 -> 256; resource 11 -> 16; teacher 60 -> 64;
  // school 450 -> 256; user 8 -> 16; comment 7.5 -> 16
  static const int GLG[7] = {6, 8, 4, 6, 8, 4, 4};

  // workspace layout (floats) — total ~307.2 MB (< round-3's 323.0 MB known fit)
  float* ws = (float*)d_ws;
  size_t offA    = 0;                                  // 414000*128 bf16 = 26,496,000 f
  size_t offB    = offA + 26496000;                    // 50000*128 f32
  size_t offT    = offB + 6400000;                     // 422000*128 bf16 = 27,008,000 f
  size_t offCnt  = offT + 27008000;                    // NROWS ints
  size_t offRp   = offCnt + NROWS;                     // NROWS+1 ints
  size_t offCol  = offRp + NROWS + 1;                  // NEDGE ints
  size_t offBkt  = offCol + NEDGE;                     // NEDGE u32
  size_t offBCnt = offBkt + NEDGE;                     // 22*NB ints
  size_t offBRp  = offBCnt + 22 * NB;                  // 22*NB+1 ints
  size_t offBCur = offBRp + 22 * NB + 4;               // 22*NB ints
  size_t offBs   = offBCur + 22 * NB;                  // 1024 ints
  size_t offWrS  = offBs + 1024;                       // 20*16384 f32
  size_t offBlS  = offWrS + (size_t)20 * 16384;        // 20*128 f32
  size_t offWt   = offBlS + (size_t)20 * HD;           // 36*16384 bf16 = 294,912 f
  size_t needFloats = offWt + 294912;
  if (ws_size < needFloats * sizeof(float)) return;

  const float* x_in[10];
  for (int t = 0; t < 10; ++t) x_in[t] = (const float*)d_in[t];
  const int* ei[13];
  for (int k = 0; k < 13; ++k) ei[k] = (const int*)d_in[10 + k];
  const float* Wl   = (const float*)d_in[23];
  const float* bl   = (const float*)d_in[24];
  const float* Wr   = (const float*)d_in[25];
  const float* linW = (const float*)d_in[26];
  const float* linb = (const float*)d_in[27];
  float* out = (float*)d_out;

  unsigned short* A  = (unsigned short*)(ws + offA);
  float*          B  = ws + offB;
  unsigned short* T  = (unsigned short*)(ws + offT);
  int* cnt  = (int*)(ws + offCnt);
  int* rp   = (int*)(ws + offRp);
  int* col  = (int*)(ws + offCol);
  unsigned* bkt = (unsigned*)(ws + offBkt);
  int* bCnt = (int*)(ws + offBCnt);
  int* bRp  = (int*)(ws + offBRp);
  int* bCur = (int*)(ws + offBCur);
  int* bs   = (int*)(ws + offBs);
  unsigned short* wt = (unsigned short*)(ws + offWt);

  auto relSrc = [&](int r) { int k = r >> 1; return (r & 1) ? FWD_D[k] : FWD_S[k]; };
  auto relDst = [&](int r) { int k = r >> 1; return (r & 1) ? FWD_S[k] : FWD_D[k]; };

  // host tables
  int segOff[22], shiftv[22], nDstv[22];
  { int acc = 0;
    for (int i = 0; i < 22; ++i) {
      int nd = NODESN[relDst(GRPREL[i])];
      segOff[i] = acc; acc += nd;
      nDstv[i] = nd;
      int s = 0; while (((nd + (1 << s) - 1) >> s) > NB) ++s;
      shiftv[i] = s;
    }
  }
  int wtSlot[26];
  for (int r = 0; r < 26; ++r) wtSlot[r] = -1;
  for (int i = 0; i < 22; ++i) wtSlot[ACT1[i]] = i;

  // 1. WrSum / blSum
  WSumArgs wa{};
  wa.Wr = Wr; wa.bl = bl; wa.WrSum = ws + offWrS; wa.blSum = ws + offBlS;
  for (int l = 0; l < 2; ++l)
    for (int t = 0; t < 10; ++t) wa.mask[l][t] = 0;
  for (int r = 0; r < 26; ++r) { int d = relDst(r); if (d <= 6) wa.mask[0][d] |= 1u << r; }
  for (int j = 0; j < 6; ++j) wa.mask[1][0] |= 1u << GRPREL[j];
  wsum_kernel<<<1280, 256, 0, stream>>>(wa);

  // 2. weight table
  WtPrepArgs wp{};
  wp.Wl = Wl; wp.WrSum = ws + offWrS; wp.wt = wt;
  for (int i = 0; i < 22; ++i) wp.code[i] = ACT1[i];
  for (int j = 0; j < 6; ++j)  wp.code[22 + j] = 26 + GRPREL[j];
  for (int d = 0; d < 7; ++d)  wp.code[28 + d] = 100 + d;
  wp.code[35] = 100 + 10;
  wtprep_kernel<<<36 * 16, 256, 0, stream>>>(wp);

  // 3. bucketed CSR build
  hipMemsetAsync(bCnt, 0, (size_t)22 * NB * sizeof(int), stream);
  BktArgs ka{};
  for (int k = 0; k < 13; ++k) ka.ei[k] = ei[k];
  ka.bkt = bkt; ka.bktCnt = bCnt; ka.bktCur = bCur;
  for (int i = 0; i < 22; ++i) { ka.rel[i] = GRPREL[i]; ka.shiftv[i] = shiftv[i]; }
  bktcount_kernel<<<22 * AWG, 256, 0, stream>>>(ka);
  scan_blk<<<2, 256, 0, stream>>>(bCnt, bRp, bs, 22 * NB);
  scan_top<<<1, 1024, 0, stream>>>(bs, 2);
  scan_add<<<(22 * NB + 255) / 256, 256, 0, stream>>>(bRp, bCur, bs, 22 * NB, NEDGE);
  bktfill_kernel<<<22 * AWG, 256, 0, stream>>>(ka);
  PlaceArgs pa{};
  pa.bkt = bkt; pa.bktRp = bRp; pa.cntG = cnt; pa.rp = rp; pa.col = col;
  for (int i = 0; i < 22; ++i) { pa.segOff[i] = segOff[i]; pa.shiftv[i] = shiftv[i]; pa.nDst[i] = nDstv[i]; }
  rowcount_kernel<<<22 * NB, 256, 0, stream>>>(pa);
  int nblk = (NROWS + 2047) / 2048;   // 747
  scan_blk<<<nblk, 256, 0, stream>>>(cnt, rp, bs, NROWS);
  scan_top<<<1, 1024, 0, stream>>>(bs, nblk);
  scan_add<<<(NROWS + 255) / 256, 256, 0, stream>>>(rp, cnt, bs, NROWS, NEDGE);
  place_kernel<<<22 * NB, 256, 0, stream>>>(pa);

  auto mgemmGrid = [&](int M) { int tl = (M + 63) / 64; return tl < 512 ? tl : 512; };
  auto gatGrid = [&](int n, int lg) { int rpb = 256 >> lg; return (n + rpb - 1) / rpb; };

  // 4. layer 1, grouped by dst type
  for (int d = 0; d < 7; ++d) {
    int nd = NODESN[d];
    MGemmArgs gi{(const void*)x_in[d], wt + ((size_t)(28 + d) << 14),
                 ws + offBlS + (size_t)d * HD, (void*)T, nd, 1, 0};
    mgemm_kernel<<<mgemmGrid(nd), 256, 0, stream>>>(gi);
    GGatArgs ga{};
    ga.T = T; ga.rp = rp; ga.col = col;
    ga.outp = (void*)(A + (size_t)AOFF[d] * HD);
    ga.n = nd; ga.nrel = GN[d]; ga.outBf16 = 1; ga.lgG = GLG[d];
    int toff = nd;
    for (int j = 0; j < GN[d]; ++j) {
      int r = GRPREL[GBASE[d] + j];
      int s = relSrc(r);
      MGemmArgs g{(const void*)x_in[s], wt + ((size_t)wtSlot[r] << 14), nullptr,
                  (void*)(T + (size_t)toff * HD), NODESN[s], 1, 0};
      mgemm_kernel<<<mgemmGrid(NODESN[s]), 256, 0, stream>>>(g);
      ga.rpOff[j] = segOff[GBASE[d] + j];
      ga.tOff[j] = toff;
      toff += NODESN[s];
    }
    ggather_kernel<<<gatGrid(nd, GLG[d]), 256, 0, stream>>>(ga);
  }

  // 5. layer 2 (course only; same CSR segments as group 0, inputs from bf16 A)
  {
    MGemmArgs gi{(const void*)A, wt + ((size_t)35 << 14),
                 ws + offBlS + (size_t)10 * HD, (void*)T, 50000, 1, 1};
    mgemm_kernel<<<mgemmGrid(50000), 256, 0, stream>>>(gi);
    GGatArgs ga{};
    ga.T = T; ga.rp = rp; ga.col = col;
    ga.outp = (void*)B;
    ga.n = 50000; ga.nrel = 6; ga.outBf16 = 0; ga.lgG = 6;
    int toff = 50000;
    for (int j = 0; j < 6; ++j) {
      int r = GRPREL[j];
      int s = relSrc(r);
      MGemmArgs g{(const void*)(A + (size_t)AOFF[s] * HD), wt + ((size_t)(22 + j) << 14),
                  nullptr, (void*)(T + (size_t)toff * HD), NODESN[s], 1, 1};
      mgemm_kernel<<<mgemmGrid(NODESN[s]), 256, 0, stream>>>(g);
      ga.rpOff[j] = segOff[j];
      ga.tOff[j] = toff;
      toff += NODESN[s];
    }
    ggather_kernel<<<gatGrid(50000, 6), 256, 0, stream>>>(ga);
  }

  // 6. final linear
  FinalArgs fa{B, linW, linb, out, 50000};
  final_kernel<<<12500, 256, 0, stream>>>(fa);
}

// Round 12
// 1071.510 us; speedup vs baseline: 1.4251x; 1.2789x over previous
//
#include <hip/hip_runtime.h>
#include <stdint.h>

#define HD 128
#define EE 300000
#define NROWS 1528000   // sum n_dst over 22 active relations (grouped by dst)
#define NEDGE 6600000   // 22 * EE
#define NB 128          // buckets per relation
#define ATILE 4096      // edges per bucketing workgroup
#define AWG 74          // ceil(EE / ATILE)
#define MAXG 8

typedef __attribute__((ext_vector_type(8))) short bf16x8;
typedef __attribute__((ext_vector_type(4))) float f32x4;
typedef __attribute__((ext_vector_type(8))) unsigned short u16x8;

static __device__ __forceinline__ unsigned short f2bf(float x) {
  union { float f; unsigned u; } v; v.f = x;
  unsigned r = v.u + 0x7FFFu + ((v.u >> 16) & 1u);
  return (unsigned short)(r >> 16);
}
static __device__ __forceinline__ float bf2f(unsigned short h) {
  union { unsigned u; float f; } v; v.u = ((unsigned)h) << 16;
  return v.f;
}

// ---------------- weight pre-sum (WrSum per (layer,type), blSum) ----------------
struct WSumArgs {
  const float* Wr;   // [2][26][128][128]
  const float* bl;   // [2][26][128]
  float* WrSum;      // [2][10][128][128]
  float* blSum;      // [2][10][128]
  unsigned int mask[2][10];
};

__global__ __launch_bounds__(256) void wsum_kernel(WSumArgs a) {
  int lt  = blockIdx.x >> 6;
  int blk = blockIdx.x & 63;
  int layer = lt / 10, type = lt % 10;
  unsigned m = a.mask[layer][type];
  int idx = blk * 256 + threadIdx.x;   // 0..16383
  float s = 0.f;
  for (int r = 0; r < 26; ++r)
    if (m & (1u << r)) s += a.Wr[((size_t)(layer * 26 + r) << 14) + idx];
  a.WrSum[((size_t)(layer * 10 + type) << 14) + idx] = s;
  if (idx < HD) {
    float b = 0.f;
    for (int r = 0; r < 26; ++r)
      if (m & (1u << r)) b += a.bl[(size_t)(layer * 26 + r) * HD + idx];
    a.blSum[(size_t)(layer * 10 + type) * HD + idx] = b;
  }
}

// ---------------- weight transpose+bf16 prep: wt[m][n][k] = bf16(src[m][k][n]) ----------------
struct WtPrepArgs {
  const float* Wl;     // [52][128][128]
  const float* WrSum;  // [20][128][128]
  unsigned short* wt;  // [36][128][128] (n-major, k contiguous)
  int code[36];        // <100: Wl flat index; >=100: WrSum flat index - 100
};

__global__ __launch_bounds__(256) void wtprep_kernel(WtPrepArgs a) {
  int m = blockIdx.x >> 4;
  int chunk = blockIdx.x & 15;
  int idx = chunk * 256 + threadIdx.x;   // float4 index 0..4095
  int c = a.code[m];
  const float* src = (c < 100) ? a.Wl + ((size_t)c << 14)
                               : a.WrSum + ((size_t)(c - 100) << 14);
  int k = idx >> 5, n0 = (idx & 31) << 2;
  float4 v = *(const float4*)(src + (size_t)k * HD + n0);
  unsigned short* d = a.wt + ((size_t)m << 14);
  d[(size_t)(n0 + 0) * HD + k] = f2bf(v.x);
  d[(size_t)(n0 + 1) * HD + k] = f2bf(v.y);
  d[(size_t)(n0 + 2) * HD + k] = f2bf(v.z);
  d[(size_t)(n0 + 3) * HD + k] = f2bf(v.w);
}

// ---------------- bucketed CSR build ----------------
struct BktArgs {
  const int* ei[13];
  unsigned* bkt;     // [NEDGE] packed entries (dstlow<<18)|src
  int* bktCnt;       // [22*NB]
  int* bktCur;       // [22*NB]
  int rel[22];
  int shiftv[22];
};

__global__ __launch_bounds__(256) void bktcount_kernel(BktArgs a) {
  __shared__ int cnt[NB];
  int ri = blockIdx.x / AWG;
  int tile = (blockIdx.x % AWG) * ATILE;
  int t = threadIdx.x;
  if (t < NB) cnt[t] = 0;
  __syncthreads();
  int r = a.rel[ri];
  const int* ei = a.ei[r >> 1];
  int flip = r & 1, sh = a.shiftv[ri];
  #pragma unroll
  for (int j = 0; j < 16; ++j) {
    int e = tile + j * 256 + t;
    if (e < EE) {
      int dst = flip ? ei[e] : ei[EE + e];
      atomicAdd(&cnt[dst >> sh], 1);
    }
  }
  __syncthreads();
  if (t < NB && cnt[t]) atomicAdd(&a.bktCnt[ri * NB + t], cnt[t]);
}

__global__ __launch_bounds__(256) void bktfill_kernel(BktArgs a) {
  __shared__ int cnt[NB];
  __shared__ int base[NB];
  int ri = blockIdx.x / AWG;
  int tile = (blockIdx.x % AWG) * ATILE;
  int t = threadIdx.x;
  if (t < NB) cnt[t] = 0;
  __syncthreads();
  int r = a.rel[ri];
  const int* ei = a.ei[r >> 1];
  int flip = r & 1, sh = a.shiftv[ri];
  unsigned mask = (1u << sh) - 1u;
  unsigned pj[16]; int bj[16];
  #pragma unroll
  for (int j = 0; j < 16; ++j) {
    int e = tile + j * 256 + t;
    if (e < EE) {
      int src = flip ? ei[EE + e] : ei[e];
      int dst = flip ? ei[e] : ei[EE + e];
      int b = dst >> sh;
      pj[j] = (((unsigned)dst & mask) << 18) | (unsigned)src;
      bj[j] = b;
      atomicAdd(&cnt[b], 1);
    } else bj[j] = -1;
  }
  __syncthreads();
  if (t < NB) base[t] = cnt[t] ? atomicAdd(&a.bktCur[ri * NB + t], cnt[t]) : 0;
  __syncthreads();
  if (t < NB) cnt[t] = base[t];
  __syncthreads();
  #pragma unroll
  for (int j = 0; j < 16; ++j) {
    if (bj[j] >= 0) {
      int pos = atomicAdd(&cnt[bj[j]], 1);
      a.bkt[pos] = pj[j];
    }
  }
}

struct PlaceArgs {
  const unsigned* bkt;
  const int* bktRp;   // [22*NB+1]
  int* cntG;          // [NROWS]
  const int* rp;      // [NROWS+1]
  int* col;           // [NEDGE]
  int segOff[22];
  int shiftv[22];
  int nDst[22];
};

__global__ __launch_bounds__(256) void rowcount_kernel(PlaceArgs a) {
  __shared__ int cnt[2048];
  int bx = blockIdx.x;
  int ri = bx >> 7, b = bx & (NB - 1);
  int sh = a.shiftv[ri], nd = a.nDst[ri];
  int rowLo = b << sh;
  if (rowLo >= nd) return;
  int rows = min(1 << sh, nd - rowLo);
  int t = threadIdx.x;
  for (int k = t; k < rows; k += 256) cnt[k] = 0;
  __syncthreads();
  int s = a.bktRp[bx], e = a.bktRp[bx + 1];
  for (int i = s + t; i < e; i += 256) atomicAdd(&cnt[a.bkt[i] >> 18], 1);
  __syncthreads();
  int rowBase = a.segOff[ri] + rowLo;
  for (int k = t; k < rows; k += 256) a.cntG[rowBase + k] = cnt[k];
}

__global__ __launch_bounds__(256) void place_kernel(PlaceArgs a) {
  __shared__ int cur[2048];
  int bx = blockIdx.x;
  int ri = bx >> 7, b = bx & (NB - 1);
  int sh = a.shiftv[ri], nd = a.nDst[ri];
  int rowLo = b << sh;
  if (rowLo >= nd) return;
  int rows = min(1 << sh, nd - rowLo);
  int t = threadIdx.x;
  int rowBase = a.segOff[ri] + rowLo;
  for (int k = t; k < rows; k += 256) cur[k] = a.rp[rowBase + k];
  __syncthreads();
  int s = a.bktRp[bx], e = a.bktRp[bx + 1];
  for (int i = s + t; i < e; i += 256) {
    unsigned u = a.bkt[i];
    int pos = atomicAdd(&cur[u >> 18], 1);
    a.col[pos] = (int)(u & 0x3FFFFu);
  }
}

// ---------------- scans ----------------
__global__ __launch_bounds__(256) void scan_blk(const int* cnt, int* rp, int* bsum, int n) {
  __shared__ int sh[256];
  int t = threadIdx.x;
  int base = blockIdx.x * 2048 + t * 8;
  int v[8]; int s = 0;
  #pragma unroll
  for (int j = 0; j < 8; ++j) { int idx = base + j; v[j] = (idx < n) ? cnt[idx] : 0; s += v[j]; }
  sh[t] = s; __syncthreads();
  for (int d = 1; d < 256; d <<= 1) {
    int x = (t >= d) ? sh[t - d] : 0;
    __syncthreads();
    sh[t] += x;
    __syncthreads();
  }
  int excl = sh[t] - s;
  if (t == 255) bsum[blockIdx.x] = sh[255];
  int run = excl;
  #pragma unroll
  for (int j = 0; j < 8; ++j) { int idx = base + j; if (idx < n) rp[idx] = run; run += v[j]; }
}

__global__ __launch_bounds__(1024) void scan_top(int* bsum, int nb) {
  __shared__ int sh[1024];
  int t = threadIdx.x;
  int s = (t < nb) ? bsum[t] : 0;
  sh[t] = s; __syncthreads();
  for (int d = 1; d < 1024; d <<= 1) {
    int x = (t >= d) ? sh[t - d] : 0;
    __syncthreads();
    sh[t] += x;
    __syncthreads();
  }
  if (t < nb) bsum[t] = sh[t] - s;
}

__global__ __launch_bounds__(256) void scan_add(int* rp, int* cur, const int* bsum, int n, int total) {
  int i = blockIdx.x * 256 + threadIdx.x;
  if (i < n) { int v = rp[i] + bsum[i >> 11]; rp[i] = v; cur[i] = v; }
  if (i == 0) rp[n] = total;
}

// single-block exclusive scan for small n (<=4096); writes rp, seeds cur, rp[n]=total
__global__ __launch_bounds__(256) void scan_small(const int* cnt, int* rp, int* cur, int n, int total) {
  __shared__ int sh[256];
  int t = threadIdx.x;
  int per = (n + 255) >> 8;      // <=16
  int base = t * per;
  int v[16]; int s = 0;
  for (int j = 0; j < per; ++j) { int idx = base + j; v[j] = (idx < n) ? cnt[idx] : 0; s += v[j]; }
  sh[t] = s; __syncthreads();
  for (int d = 1; d < 256; d <<= 1) {
    int x = (t >= d) ? sh[t - d] : 0;
    __syncthreads();
    sh[t] += x;
    __syncthreads();
  }
  int run = sh[t] - s;
  for (int j = 0; j < per; ++j) {
    int idx = base + j;
    if (idx < n) { rp[idx] = run; cur[idx] = run; }
    run += v[j];
  }
  if (t == 255) rp[n] = total;
}

// ---------------- batched bf16 MFMA GEMM ----------------
// Up to MAXG GEMMs per launch: C_g[M_g x 128] = A_g @ W_g (+bias_g), all outputs bf16.
// Each block serves one GEMM (by block range), stages its W once, grid-strides tiles.
struct MGemmBatch {
  const void* A[MAXG];
  const unsigned short* Wt[MAXG];
  const float* bias[MAXG];
  unsigned short* C[MAXG];
  int M[MAXG];
  int blkStart[MAXG];
  int nblk[MAXG];
  int ng, inBf16;
};

__global__ __launch_bounds__(256) void mgemmb_kernel(MGemmBatch gb) {
  __shared__ unsigned short As[64 * HD];   // [r][k] bf16, byte ^ ((r&7)<<4)
  __shared__ unsigned short Wsm[HD * HD];  // [n][k] bf16, byte ^ ((n&7)<<4)
  const int t = threadIdx.x;
  int g = 0;
  while (g + 1 < gb.ng && (int)blockIdx.x >= gb.blkStart[g + 1]) ++g;
  const unsigned short* Wt = gb.Wt[g];
  const float* bias = gb.bias[g];
  unsigned short* C = gb.C[g];
  const int M = gb.M[g];
  const int tiles = (M + 63) >> 6;

  // stage W once per block (8 x 16B per thread)
  #pragma unroll
  for (int it = 0; it < 8; ++it) {
    int i8 = t + it * 256;
    int byteoff = i8 << 4;
    int n = byteoff >> 8;
    u16x8 w = *(const u16x8*)((const char*)Wt + byteoff);
    *(u16x8*)((char*)Wsm + (byteoff ^ ((n & 7) << 4))) = w;
  }

  const int wv = t >> 6;
  const int lane = t & 63;
  const int lr = lane & 15;
  const int lk = lane >> 4;

  for (int tile = blockIdx.x - gb.blkStart[g]; tile < tiles; tile += gb.nblk[g]) {
    const int rowBase = tile << 6;
    __syncthreads();   // prior tile's LDS reads done (and W ready on first iter)

    if (gb.inBf16) {
      const unsigned short* Ab = (const unsigned short*)gb.A[g];
      #pragma unroll
      for (int it = 0; it < 4; ++it) {
        int i8 = t + it * 256;
        int byteoff = i8 << 4;
        int r = byteoff >> 8;
        int gr = rowBase + r; if (gr >= M) gr = M - 1;
        u16x8 h = *(const u16x8*)((const char*)Ab + (size_t)gr * 256 + (byteoff & 255));
        *(u16x8*)((char*)As + (byteoff ^ ((r & 7) << 4))) = h;
      }
    } else {
      const float* Af = (const float*)gb.A[g];
      #pragma unroll
      for (int it = 0; it < 4; ++it) {
        int i8 = t + it * 256;
        int byteoff = i8 << 4;
        int r = byteoff >> 8;
        int gr = rowBase + r; if (gr >= M) gr = M - 1;
        int fo = (byteoff & 255) >> 1;
        float4 v0 = *(const float4*)(Af + (size_t)gr * HD + fo);
        float4 v1 = *(const float4*)(Af + (size_t)gr * HD + fo + 4);
        u16x8 h;
        h[0] = f2bf(v0.x); h[1] = f2bf(v0.y); h[2] = f2bf(v0.z); h[3] = f2bf(v0.w);
        h[4] = f2bf(v1.x); h[5] = f2bf(v1.y); h[6] = f2bf(v1.z); h[7] = f2bf(v1.w);
        *(u16x8*)((char*)As + (byteoff ^ ((r & 7) << 4))) = h;
      }
    }
    __syncthreads();

    bf16x8 afr[4];
    #pragma unroll
    for (int kc = 0; kc < 4; ++kc) {
      int r = wv * 16 + lr;
      int byte = r * 256 + kc * 64 + lk * 16;
      afr[kc] = *(const bf16x8*)((char*)As + (byte ^ ((r & 7) << 4)));
    }

    f32x4 acc[8];
    #pragma unroll
    for (int nt = 0; nt < 8; ++nt) acc[nt] = (f32x4){0.f, 0.f, 0.f, 0.f};

    #pragma unroll
    for (int nt = 0; nt < 8; ++nt) {
      int n = nt * 16 + lr;
      int nbyte = n * 256 + lk * 16;
      int nswz = (n & 7) << 4;
      #pragma unroll
      for (int kc = 0; kc < 4; ++kc) {
        bf16x8 bfr = *(const bf16x8*)((char*)Wsm + ((nbyte + kc * 64) ^ nswz));
        acc[nt] = __builtin_amdgcn_mfma_f32_16x16x32_bf16(afr[kc], bfr, acc[nt], 0, 0, 0);
      }
    }

    #pragma unroll
    for (int nt = 0; nt < 8; ++nt) {
      int col = nt * 16 + lr;
      float bv = bias ? bias[col] : 0.f;
      #pragma unroll
      for (int q = 0; q < 4; ++q) {
        int grow = rowBase + wv * 16 + lk * 4 + q;
        if (grow < M) C[(size_t)grow * HD + col] = f2bf(acc[nt][q] + bv);
      }
    }
  }
}

// ---------------- grouped gather (degree-adaptive lanes-per-row) ----------------
struct GGatArgs {
  const unsigned short* T;   // group T arena (init at rows [0,n))
  const int* rp;             // global rowptr
  const int* col;            // global col (src)
  void* outp;                // bf16 (L1) or f32 (L2)
  int n, nrel, outBf16, lgG; // lgG = log2(gsize) in {4,6,8}
  int rpOff[6];
  int tOff[6];
};

__global__ __launch_bounds__(256) void ggather_kernel(GGatArgs g) {
  __shared__ float red[3][128];
  const int gsize = 1 << g.lgG;
  const int npar = gsize >> 4;
  const int gid = (int)((blockIdx.x * 256 + threadIdx.x) >> g.lgG);
  const int within = threadIdx.x & (gsize - 1);
  const int p = within >> 4;
  const int cl = within & 15;
  const bool active = gid < g.n;

  float acc[8], acc2[8];
  #pragma unroll
  for (int k = 0; k < 8; ++k) { acc[k] = 0.f; acc2[k] = 0.f; }

  if (active) {
    #pragma unroll
    for (int j = 0; j < 6; ++j) {
      if (j < g.nrel) {
        int base = g.rpOff[j] + gid;
        int s = g.rp[base], e = g.rp[base + 1];
        if (s < e) {
          float inv = 1.f / (float)(e - s);
          const unsigned short* Tj = g.T + ((size_t)g.tOff[j] << 7);
          int i = s + p;
          for (; i + npar < e; i += 2 * npar) {
            int s0 = g.col[i], s1 = g.col[i + npar];
            u16x8 v0 = *(const u16x8*)(Tj + ((size_t)s0 << 7) + cl * 8);
            u16x8 v1 = *(const u16x8*)(Tj + ((size_t)s1 << 7) + cl * 8);
            #pragma unroll
            for (int k = 0; k < 8; ++k) {
              acc[k]  = fmaf(bf2f(v0[k]), inv, acc[k]);
              acc2[k] = fmaf(bf2f(v1[k]), inv, acc2[k]);
            }
          }
          if (i < e) {
            int s0 = g.col[i];
            u16x8 v0 = *(const u16x8*)(Tj + ((size_t)s0 << 7) + cl * 8);
            #pragma unroll
            for (int k = 0; k < 8; ++k) acc[k] = fmaf(bf2f(v0[k]), inv, acc[k]);
          }
        }
      }
    }
  }
  #pragma unroll
  for (int k = 0; k < 8; ++k) acc[k] += acc2[k];

  if (npar > 1) {
    #pragma unroll
    for (int k = 0; k < 8; ++k) {
      acc[k] += __shfl_xor(acc[k], 16);
      acc[k] += __shfl_xor(acc[k], 32);
    }
    if (gsize == 256) {
      int wvi = threadIdx.x >> 6;
      if (wvi > 0 && (threadIdx.x & 63) < 16) {
        #pragma unroll
        for (int k = 0; k < 8; ++k) red[wvi - 1][cl * 8 + k] = acc[k];
      }
      __syncthreads();
      if (threadIdx.x < 16) {
        #pragma unroll
        for (int k = 0; k < 8; ++k)
          acc[k] += red[0][cl * 8 + k] + red[1][cl * 8 + k] + red[2][cl * 8 + k];
      }
    }
  }

  if (active && within < 16) {
    u16x8 iv = *(const u16x8*)(g.T + ((size_t)gid << 7) + cl * 8);
    if (g.outBf16) {
      u16x8 o;
      #pragma unroll
      for (int k = 0; k < 8; ++k)
        o[k] = f2bf(fmaxf(acc[k] + bf2f(iv[k]), 0.f));
      *(u16x8*)((unsigned short*)g.outp + ((size_t)gid << 7) + cl * 8) = o;
    } else {
      float* op = (float*)g.outp + ((size_t)gid << 7) + cl * 8;
      float v[8];
      #pragma unroll
      for (int k = 0; k < 8; ++k) v[k] = fmaxf(acc[k] + bf2f(iv[k]), 0.f);
      *(float4*)op       = make_float4(v[0], v[1], v[2], v[3]);
      *(float4*)(op + 4) = make_float4(v[4], v[5], v[6], v[7]);
    }
  }
}

// ---------------- final: out[M x 64] = X[M x 128] @ W[128 x 64] + b ----------------
struct FinalArgs { const float* X; const float* W; const float* b; float* out; int M; };

__global__ __launch_bounds__(256) void final_kernel(FinalArgs f) {
  __shared__ float xs[512];
  int t = threadIdx.x;
  int row0 = blockIdx.x << 2;
  {
    int li = t << 1;
    int lrow = li >> 7;
    float2 v = make_float2(0.f, 0.f);
    if (row0 + lrow < f.M) v = *(const float2*)(f.X + (size_t)(row0 + lrow) * HD + (li & 127));
    *(float2*)(&xs[li]) = v;
  }
  __syncthreads();
  int r = t >> 6, c = t & 63;
  float acc = 0.f;
  const float* xrow = &xs[r << 7];
  #pragma unroll 8
  for (int k = 0; k < HD; ++k) acc = fmaf(xrow[k], f.W[k * 64 + c], acc);
  if (row0 + r < f.M) f.out[(size_t)(row0 + r) * 64 + c] = acc + f.b[c];
}

// ---------------- host ----------------
extern "C" void kernel_launch(void* const* d_in, const int* in_sizes, int n_in,
                              void* d_out, int out_size, void* d_ws, size_t ws_size,
                              hipStream_t stream) {
  static const int NODESN[10] = {50000, 2000, 80000, 10000, 2000, 150000, 120000, 100000, 60000, 40000};
  static const int FWD_S[13] = {0, 0, 0, 0, 0, 0, 6, 5, 5, 4, 4, 2, 2};
  static const int FWD_D[13] = {1, 2, 3, 4, 5, 6, 7, 6, 7, 5, 3, 8, 9};
  static const int ACT1[22] = {0,1,2,3,4,5,6,7,8,9,10,11,13,14,15,17,18,19,20,21,23,25};
  // relations grouped by dst type (course, field, resource, teacher, school, user, comment):
  static const int GRPREL[22] = {1,3,5,7,9,11,  0,  2,23,25,  4,20,  6,19,21,  8,15,17,18,  10,13,14};
  static const int GN[7]    = {6, 1, 3, 2, 3, 4, 3};
  static const int GBASE[7] = {0, 6, 7, 10, 12, 15, 19};
  static const int AOFF[7]  = {0, 50000, 52000, 132000, 142000, 144000, 294000};
  // lanes-per-row = 1<<GLG (degree-adaptive)
  static const int GLG[7] = {6, 8, 4, 6, 8, 4, 4};

  // workspace layout (floats) — total ~307.2 MB (< round-3's 323.0 MB known fit)
  float* ws = (float*)d_ws;
  size_t offA    = 0;                                  // 414000*128 bf16 = 26,496,000 f
  size_t offB    = offA + 26496000;                    // 50000*128 f32
  size_t offT    = offB + 6400000;                     // 422000*128 bf16 = 27,008,000 f
  size_t offCnt  = offT + 27008000;                    // NROWS ints
  size_t offRp   = offCnt + NROWS;                     // NROWS+1 ints
  size_t offCol  = offRp + NROWS + 1;                  // NEDGE ints
  size_t offBkt  = offCol + NEDGE;                     // NEDGE u32
  size_t offBCnt = offBkt + NEDGE;                     // 22*NB ints
  size_t offBRp  = offBCnt + 22 * NB;                  // 22*NB+1 ints
  size_t offBCur = offBRp + 22 * NB + 4;               // 22*NB ints
  size_t offBs   = offBCur + 22 * NB;                  // 1024 ints
  size_t offWrS  = offBs + 1024;                       // 20*16384 f32
  size_t offBlS  = offWrS + (size_t)20 * 16384;        // 20*128 f32
  size_t offWt   = offBlS + (size_t)20 * HD;           // 36*16384 bf16 = 294,912 f
  size_t needFloats = offWt + 294912;
  if (ws_size < needFloats * sizeof(float)) return;

  const float* x_in[10];
  for (int t = 0; t < 10; ++t) x_in[t] = (const float*)d_in[t];
  const int* ei[13];
  for (int k = 0; k < 13; ++k) ei[k] = (const int*)d_in[10 + k];
  const float* Wl   = (const float*)d_in[23];
  const float* bl   = (const float*)d_in[24];
  const float* Wr   = (const float*)d_in[25];
  const float* linW = (const float*)d_in[26];
  const float* linb = (const float*)d_in[27];
  float* out = (float*)d_out;

  unsigned short* A  = (unsigned short*)(ws + offA);
  float*          B  = ws + offB;
  unsigned short* T  = (unsigned short*)(ws + offT);
  int* cnt  = (int*)(ws + offCnt);
  int* rp   = (int*)(ws + offRp);
  int* col  = (int*)(ws + offCol);
  unsigned* bkt = (unsigned*)(ws + offBkt);
  int* bCnt = (int*)(ws + offBCnt);
  int* bRp  = (int*)(ws + offBRp);
  int* bCur = (int*)(ws + offBCur);
  int* bs   = (int*)(ws + offBs);
  unsigned short* wt = (unsigned short*)(ws + offWt);

  auto relSrc = [&](int r) { int k = r >> 1; return (r & 1) ? FWD_D[k] : FWD_S[k]; };
  auto relDst = [&](int r) { int k = r >> 1; return (r & 1) ? FWD_S[k] : FWD_D[k]; };

  // host tables
  int segOff[22], shiftv[22], nDstv[22];
  { int acc = 0;
    for (int i = 0; i < 22; ++i) {
      int nd = NODESN[relDst(GRPREL[i])];
      segOff[i] = acc; acc += nd;
      nDstv[i] = nd;
      int s = 0; while (((nd + (1 << s) - 1) >> s) > NB) ++s;
      shiftv[i] = s;
    }
  }
  int wtSlot[26];
  for (int r = 0; r < 26; ++r) wtSlot[r] = -1;
  for (int i = 0; i < 22; ++i) wtSlot[ACT1[i]] = i;

  // 1. WrSum / blSum
  WSumArgs wa{};
  wa.Wr = Wr; wa.bl = bl; wa.WrSum = ws + offWrS; wa.blSum = ws + offBlS;
  for (int l = 0; l < 2; ++l)
    for (int t = 0; t < 10; ++t) wa.mask[l][t] = 0;
  for (int r = 0; r < 26; ++r) { int d = relDst(r); if (d <= 6) wa.mask[0][d] |= 1u << r; }
  for (int j = 0; j < 6; ++j) wa.mask[1][0] |= 1u << GRPREL[j];
  wsum_kernel<<<1280, 256, 0, stream>>>(wa);

  // 2. weight table
  WtPrepArgs wp{};
  wp.Wl = Wl; wp.WrSum = ws + offWrS; wp.wt = wt;
  for (int i = 0; i < 22; ++i) wp.code[i] = ACT1[i];
  for (int j = 0; j < 6; ++j)  wp.code[22 + j] = 26 + GRPREL[j];
  for (int d = 0; d < 7; ++d)  wp.code[28 + d] = 100 + d;
  wp.code[35] = 100 + 10;
  wtprep_kernel<<<36 * 16, 256, 0, stream>>>(wp);

  // 3. bucketed CSR build
  hipMemsetAsync(bCnt, 0, (size_t)22 * NB * sizeof(int), stream);
  BktArgs ka{};
  for (int k = 0; k < 13; ++k) ka.ei[k] = ei[k];
  ka.bkt = bkt; ka.bktCnt = bCnt; ka.bktCur = bCur;
  for (int i = 0; i < 22; ++i) { ka.rel[i] = GRPREL[i]; ka.shiftv[i] = shiftv[i]; }
  bktcount_kernel<<<22 * AWG, 256, 0, stream>>>(ka);
  scan_small<<<1, 256, 0, stream>>>(bCnt, bRp, bCur, 22 * NB, NEDGE);
  bktfill_kernel<<<22 * AWG, 256, 0, stream>>>(ka);
  PlaceArgs pa{};
  pa.bkt = bkt; pa.bktRp = bRp; pa.cntG = cnt; pa.rp = rp; pa.col = col;
  for (int i = 0; i < 22; ++i) { pa.segOff[i] = segOff[i]; pa.shiftv[i] = shiftv[i]; pa.nDst[i] = nDstv[i]; }
  rowcount_kernel<<<22 * NB, 256, 0, stream>>>(pa);
  int nblk = (NROWS + 2047) / 2048;   // 747
  scan_blk<<<nblk, 256, 0, stream>>>(cnt, rp, bs, NROWS);
  scan_top<<<1, 1024, 0, stream>>>(bs, nblk);
  scan_add<<<(NROWS + 255) / 256, 256, 0, stream>>>(rp, cnt, bs, NROWS, NEDGE);
  place_kernel<<<22 * NB, 256, 0, stream>>>(pa);

  auto gatGrid = [&](int n, int lg) { int rpb = 256 >> lg; return (n + rpb - 1) / rpb; };

  // batched mgemm launcher: init + relations of one group in ONE launch
  auto launchGroup = [&](int inBf16, const void* initA, int initSlot, const float* initBias,
                         int nd, const void* srcA[6], const int srcSlot[6], const int srcM[6],
                         int nrel) {
    MGemmBatch mb{};
    mb.inBf16 = inBf16;
    int tiles[MAXG]; long long tot = 0; int ng = 0;
    auto add = [&](const void* Ap, int slot, const float* bp, unsigned short* Cp, int M) {
      mb.A[ng] = Ap; mb.Wt[ng] = wt + ((size_t)slot << 14); mb.bias[ng] = bp;
      mb.C[ng] = Cp; mb.M[ng] = M;
      tiles[ng] = (M + 63) >> 6; tot += tiles[ng]; ++ng;
    };
    add(initA, initSlot, initBias, T, nd);
    int toff = nd;
    for (int j = 0; j < nrel; ++j) {
      add(srcA[j], srcSlot[j], nullptr, T + (size_t)toff * HD, srcM[j]);
      toff += srcM[j];
    }
    mb.ng = ng;
    int target = (int)(tot < 2560 ? tot : 2560);
    int grid = 0;
    for (int g2 = 0; g2 < ng; ++g2) {
      int nb2 = (int)((long long)tiles[g2] * target / tot);
      if (nb2 < 1) nb2 = 1;
      if (nb2 > tiles[g2]) nb2 = tiles[g2];
      mb.nblk[g2] = nb2; mb.blkStart[g2] = grid; grid += nb2;
    }
    mgemmb_kernel<<<grid, 256, 0, stream>>>(mb);
  };

  // 4. layer 1, grouped by dst type
  for (int d = 0; d < 7; ++d) {
    int nd = NODESN[d];
    const void* srcA[6]; int srcSlot[6], srcM[6];
    GGatArgs ga{};
    ga.T = T; ga.rp = rp; ga.col = col;
    ga.outp = (void*)(A + (size_t)AOFF[d] * HD);
    ga.n = nd; ga.nrel = GN[d]; ga.outBf16 = 1; ga.lgG = GLG[d];
    int toff = nd;
    for (int j = 0; j < GN[d]; ++j) {
      int r = GRPREL[GBASE[d] + j];
      int s = relSrc(r);
      srcA[j] = (const void*)x_in[s]; srcSlot[j] = wtSlot[r]; srcM[j] = NODESN[s];
      ga.rpOff[j] = segOff[GBASE[d] + j];
      ga.tOff[j] = toff;
      toff += NODESN[s];
    }
    launchGroup(0, (const void*)x_in[d], 28 + d, ws + offBlS + (size_t)d * HD,
                nd, srcA, srcSlot, srcM, GN[d]);
    ggather_kernel<<<gatGrid(nd, GLG[d]), 256, 0, stream>>>(ga);
  }

  // 5. layer 2 (course only; same CSR segments as group 0, inputs from bf16 A)
  {
    const void* srcA[6]; int srcSlot[6], srcM[6];
    GGatArgs ga{};
    ga.T = T; ga.rp = rp; ga.col = col;
    ga.outp = (void*)B;
    ga.n = 50000; ga.nrel = 6; ga.outBf16 = 0; ga.lgG = 6;
    int toff = 50000;
    for (int j = 0; j < 6; ++j) {
      int r = GRPREL[j];
      int s = relSrc(r);
      srcA[j] = (const void*)(A + (size_t)AOFF[s] * HD); srcSlot[j] = 22 + j; srcM[j] = NODESN[s];
      ga.rpOff[j] = segOff[j];
      ga.tOff[j] = toff;
      toff += NODESN[s];
    }
    launchGroup(1, (const void*)A, 35, ws + offBlS + (size_t)10 * HD,
                50000, srcA, srcSlot, srcM, 6);
    ggather_kernel<<<gatGrid(50000, 6), 256, 0, stream>>>(ga);
  }

  // 6. final linear
  FinalArgs fa{B, linW, linb, out, 50000};
  final_kernel<<<12500, 256, 0, stream>>>(fa);
}